// Round 3
// baseline (236.376 us; speedup 1.0000x reference)
//
#include <hip/hip_runtime.h>

using uint = unsigned int;
using ushort = unsigned short;

typedef float f32x4 __attribute__((ext_vector_type(4)));
typedef float f32x16 __attribute__((ext_vector_type(16)));
typedef uint u32x4 __attribute__((ext_vector_type(4)));
using short8 = __attribute__((ext_vector_type(8))) short;

// round-to-nearest-even f32 -> bf16 (as ushort)
__device__ __forceinline__ ushort f2bf(float f) {
  uint u = __float_as_uint(f);
  u += 0x7fffu + ((u >> 16) & 1u);
  return (ushort)(u >> 16);
}

// async global->LDS, 16B per lane; LDS dest must be linear (wave base + lane*16)
#define GLOAD_LDS16(gptr, lptr)                                                   \
  __builtin_amdgcn_global_load_lds(                                               \
      (const __attribute__((address_space(1))) void*)(gptr),                      \
      (__attribute__((address_space(3))) void*)(lptr), 16, 0, 0)

// XOR swizzle: spread 8 consecutive 128B rows across 8 16B slots (involution)
__device__ __forceinline__ int swz(int o) { return o ^ (((o >> 7) & 7) << 4); }

// ---------------------------------------------------------------- cast kernel
__global__ void cast_f32_to_bf16(const float* __restrict__ in,
                                 ushort* __restrict__ out, int n4) {
  int stride = gridDim.x * blockDim.x;
  for (int i = blockIdx.x * blockDim.x + threadIdx.x; i < n4; i += stride) {
    float4 v = reinterpret_cast<const float4*>(in)[i];
    ushort4 o;
    o.x = f2bf(v.x); o.y = f2bf(v.y); o.z = f2bf(v.z); o.w = f2bf(v.w);
    reinterpret_cast<ushort4*>(out)[i] = o;
  }
}

// ---------------- 8-phase, 2-tile-deep pipelined GEMM mainloop ---------------
// C[m,n] = sum_k A[m,k]*W[n,k]; A,W bf16 row-major K-contiguous; K % 64 == 0.
// BM x 256 tile, BK=64, 512 threads = 8 waves (2 row-groups x 4 col-groups).
// LDS: 2 bufs x [A: BM*128 B | B: 32768 B]. T2 swizzle via linear gload dest +
// inverse-swizzled global source + swizzled ds_read (both-sides rule).
// Tile t read from buf[t&1] in 4 C-quadrant phases; tile t+2 staged into the
// SAME buffer's regions after their last read (A quarters free after P1/P3,
// B after P2); boundary s_waitcnt vmcnt(TL) keeps t+2's loads in flight (T4).
template <int BM>
__device__ __forceinline__ void gemm8p(const char* Ab, const char* Bb, int K,
                                       char* lds, f32x4 (&acc)[BM / 32][4]) {
  constexpr int MI = BM / 32;   // A-frag row-tiles per wave (8 or 4)
  constexpr int MH = MI / 2;
  constexpr int ABYTES = BM * 128;
  constexpr int BUFB = ABYTES + 32768;
  constexpr int NAU = BM / 64;  // A stage units of 64 rows (4 or 2)
  constexpr int TL = NAU + 4;   // gload instrs per tile (8 or 6)

  const int tid = threadIdx.x;
  const int lane = tid & 63;
  const int wm = (tid >> 8) & 1;
  const int wn = (tid >> 6) & 3;
  const int lr = lane & 15, lgk = lane >> 4;
  const size_t K2 = (size_t)K * 2;
  const int nt = K >> 6;

  // per-thread pre-swizzled global source pointers (dest is linear)
  const char* srcA[NAU];
#pragma unroll
  for (int u = 0; u < NAU; ++u) {
    int d = u * 8192 + tid * 16, s = swz(d);
    srcA[u] = Ab + (size_t)(s >> 7) * K2 + (s & 127);
  }
  const char* srcB[4];
#pragma unroll
  for (int u = 0; u < 4; ++u) {
    int d = u * 8192 + tid * 16, s = swz(d);
    srcB[u] = Bb + (size_t)(s >> 7) * K2 + (s & 127);
  }
  char* dstA = lds + tid * 16;
  char* dstB = lds + ABYTES + tid * 16;

  auto stA = [&](int buf, int u, int t) {
    GLOAD_LDS16(srcA[u] + (size_t)t * 128, dstA + buf * BUFB + u * 8192);
  };
  auto stB = [&](int buf, int u, int t) {
    GLOAD_LDS16(srcB[u] + (size_t)t * 128, dstB + buf * BUFB + u * 8192);
  };
  auto rdA = [&](int buf, int mi, int kk) -> short8 {
    int o = (wm * (BM / 2) + mi * 16 + lr) * 128 + kk * 64 + lgk * 16;
    return *reinterpret_cast<const short8*>(lds + buf * BUFB + swz(o));
  };
  auto rdB = [&](int buf, int ni, int kk) -> short8 {
    int o = (wn * 64 + ni * 16 + lr) * 128 + kk * 64 + lgk * 16;
    return *reinterpret_cast<const short8*>(lds + buf * BUFB + ABYTES + swz(o));
  };

  // prologue: stage tiles 0 and 1; wait tile 0 (tile 1 stays in flight)
#pragma unroll
  for (int u = 0; u < NAU; ++u) stA(0, u, 0);
#pragma unroll
  for (int u = 0; u < 4; ++u) stB(0, u, 0);
#pragma unroll
  for (int u = 0; u < NAU; ++u) stA(1, u, 1);
#pragma unroll
  for (int u = 0; u < 4; ++u) stB(1, u, 1);
  asm volatile("s_waitcnt vmcnt(%0)" ::"n"(TL) : "memory");
  __builtin_amdgcn_s_barrier();

  short8 af[MH][2], bf[4][2];

  for (int t = 0; t < nt; ++t) {
    const int c = t & 1;
    const bool pf = (t + 2 < nt);

    // ---- P1: read af(h0) + bf(all ni lo); MFMA quadrant (h0, n0-1)
#pragma unroll
    for (int mi = 0; mi < MH; ++mi) { af[mi][0] = rdA(c, mi, 0); af[mi][1] = rdA(c, mi, 1); }
#pragma unroll
    for (int ni = 0; ni < 2; ++ni) { bf[ni][0] = rdB(c, ni, 0); bf[ni][1] = rdB(c, ni, 1); }
    __builtin_amdgcn_s_barrier();
    __builtin_amdgcn_s_setprio(1);
#pragma unroll
    for (int mi = 0; mi < MH; ++mi)
#pragma unroll
      for (int ni = 0; ni < 2; ++ni)
#pragma unroll
        for (int kk = 0; kk < 2; ++kk)
          acc[mi][ni] = __builtin_amdgcn_mfma_f32_16x16x32_bf16(af[mi][kk], bf[ni][kk], acc[mi][ni], 0, 0, 0);
    __builtin_amdgcn_s_setprio(0);
    __builtin_amdgcn_s_barrier();

    // ---- P2: read bf(n2-3); stage A quarters freed by P1; MFMA (h0, n2-3)
#pragma unroll
    for (int ni = 2; ni < 4; ++ni) { bf[ni][0] = rdB(c, ni, 0); bf[ni][1] = rdB(c, ni, 1); }
    if (pf) {
      if constexpr (BM == 256) { stA(c, 0, t + 2); stA(c, 2, t + 2); }
    }
    __builtin_amdgcn_s_barrier();
    __builtin_amdgcn_s_setprio(1);
#pragma unroll
    for (int mi = 0; mi < MH; ++mi)
#pragma unroll
      for (int ni = 2; ni < 4; ++ni)
#pragma unroll
        for (int kk = 0; kk < 2; ++kk)
          acc[mi][ni] = __builtin_amdgcn_mfma_f32_16x16x32_bf16(af[mi][kk], bf[ni][kk], acc[mi][ni], 0, 0, 0);
    __builtin_amdgcn_s_setprio(0);
    __builtin_amdgcn_s_barrier();

    // ---- P3: read af(h1); stage all B (freed by P2); MFMA (h1, n0-1)
#pragma unroll
    for (int mi = 0; mi < MH; ++mi) { af[mi][0] = rdA(c, MH + mi, 0); af[mi][1] = rdA(c, MH + mi, 1); }
    if (pf) {
#pragma unroll
      for (int u = 0; u < 4; ++u) stB(c, u, t + 2);
    }
    __builtin_amdgcn_s_barrier();
    __builtin_amdgcn_s_setprio(1);
#pragma unroll
    for (int mi = 0; mi < MH; ++mi)
#pragma unroll
      for (int ni = 0; ni < 2; ++ni)
#pragma unroll
        for (int kk = 0; kk < 2; ++kk)
          acc[MH + mi][ni] = __builtin_amdgcn_mfma_f32_16x16x32_bf16(af[mi][kk], bf[ni][kk], acc[MH + mi][ni], 0, 0, 0);
    __builtin_amdgcn_s_setprio(0);
    __builtin_amdgcn_s_barrier();

    // ---- P4: stage A quarters freed by P3; MFMA (h1, n2-3); boundary wait
    if (pf) {
      if constexpr (BM == 256) { stA(c, 1, t + 2); stA(c, 3, t + 2); }
      else                     { stA(c, 0, t + 2); stA(c, 1, t + 2); }
    }
    __builtin_amdgcn_s_setprio(1);
#pragma unroll
    for (int mi = 0; mi < MH; ++mi)
#pragma unroll
      for (int ni = 2; ni < 4; ++ni)
#pragma unroll
        for (int kk = 0; kk < 2; ++kk)
          acc[MH + mi][ni] = __builtin_amdgcn_mfma_f32_16x16x32_bf16(af[mi][kk], bf[ni][kk], acc[MH + mi][ni], 0, 0, 0);
    __builtin_amdgcn_s_setprio(0);
    if (t + 1 < nt) {
      if (pf) { asm volatile("s_waitcnt vmcnt(%0)" ::"n"(TL) : "memory"); }
      else    { asm volatile("s_waitcnt vmcnt(0)" ::: "memory"); }
      __builtin_amdgcn_s_barrier();
    }
  }
}

// -------------------------------------------------------------- fused QKV GEMM
// 192 blocks: bx 0-7 Q (N=2048), 8-9 K (512), 10-11 V (512, transposed out)
__global__ __launch_bounds__(512) void qkv_gemm8(
    const ushort* __restrict__ Xb, const ushort* __restrict__ Wq,
    const ushort* __restrict__ Wk, const ushort* __restrict__ Wv,
    const float* __restrict__ bq, const float* __restrict__ bk,
    const float* __restrict__ bv, ushort* __restrict__ Qb,
    ushort* __restrict__ Kb, ushort* __restrict__ Vt) {
  __shared__ char lds[2 * (256 * 128 + 32768)];  // 128 KiB
  int id = blockIdx.x;
  id = (id & 7) * 24 + (id >> 3);  // XCD-contiguous swizzle (192 % 8 == 0)
  const int bx = id % 12, by = id / 12;

  const ushort* W; const float* bias; ushort* out;
  int n0, mode, ldo;
  if (bx < 8)       { W = Wq; bias = bq; out = Qb; n0 = bx * 256;        mode = 0; ldo = 2048; }
  else if (bx < 10) { W = Wk; bias = bk; out = Kb; n0 = (bx - 8) * 256;  mode = 0; ldo = 512; }
  else              { W = Wv; bias = bv; out = Vt; n0 = (bx - 10) * 256; mode = 1; ldo = 0; }

  f32x4 acc[8][4] = {};
  gemm8p<256>((const char*)(Xb + (size_t)by * 256 * 2048),
              (const char*)(W + (size_t)n0 * 2048), 2048, lds, acc);

  const int lane = threadIdx.x & 63;
  const int wm = (threadIdx.x >> 8) & 1, wn = (threadIdx.x >> 6) & 3;
  const int r0 = by * 256 + wm * 128 + (lane >> 4) * 4;
  const int c0 = wn * 64 + (lane & 15);
#pragma unroll
  for (int mi = 0; mi < 8; ++mi)
#pragma unroll
    for (int ni = 0; ni < 4; ++ni) {
      const int col = c0 + ni * 16;
      const float bb = bias[n0 + col];
#pragma unroll
      for (int j = 0; j < 4; ++j) {
        const int row = r0 + mi * 16 + j;
        const float v = acc[mi][ni][j] + bb;
        if (mode == 0) {
          out[(size_t)row * ldo + n0 + col] = f2bf(v);
        } else {  // V transposed: Vt[(b*512 + n)*2048 + s]
          const int b = row >> 11, s = row & 2047;
          out[((size_t)(b * 512 + n0 + col) << 11) + s] = f2bf(v);
        }
      }
    }
}

// ------------------------------------------------------------ out-projection
// 256 blocks: BM=128 x BN=256 (full machine at M=4096, N=2048)
__global__ __launch_bounds__(512) void out_gemm8(const ushort* __restrict__ Mid,
                                                 const ushort* __restrict__ Wo,
                                                 const float* __restrict__ bo,
                                                 float* __restrict__ Out) {
  __shared__ char lds[2 * (128 * 128 + 32768)];  // 96 KiB
  int id = blockIdx.x;
  id = (id & 7) * 32 + (id >> 3);  // XCD swizzle (256 % 8 == 0)
  const int bx = id % 8, by = id / 8;

  f32x4 acc[4][4] = {};
  gemm8p<128>((const char*)(Mid + (size_t)by * 128 * 2048),
              (const char*)(Wo + (size_t)bx * 256 * 2048), 2048, lds, acc);

  const int lane = threadIdx.x & 63;
  const int wm = (threadIdx.x >> 8) & 1, wn = (threadIdx.x >> 6) & 3;
  const int r0 = by * 128 + wm * 64 + (lane >> 4) * 4;
  const int c0 = bx * 256 + wn * 64 + (lane & 15);
#pragma unroll
  for (int mi = 0; mi < 4; ++mi)
#pragma unroll
    for (int ni = 0; ni < 4; ++ni) {
      const int col = c0 + ni * 16;
      const float bb = bo[col];
#pragma unroll
      for (int j = 0; j < 4; ++j)
        Out[(size_t)(r0 + mi * 16 + j) * 2048 + col] = acc[mi][ni][j] + bb;
    }
}

// ------------------------------------------------------------ flash attention
// Swapped-QK^T 32x32 structure; 4 waves x 32 q-rows; KVBLK=64 double-buffered.
__global__ __launch_bounds__(256, 2) void attn_fwd(const ushort* __restrict__ Q,
                                                   const ushort* __restrict__ Kb,
                                                   const ushort* __restrict__ Vt,
                                                   ushort* __restrict__ Mid) {
  __shared__ ushort Ks[2][64 * 128];
  __shared__ ushort Vs[2][128 * 64];

  const int tid = threadIdx.x, lane = tid & 63, wave = tid >> 6;
  const int h = blockIdx.y, b = blockIdx.z, g = h >> 2;
  const int q0w = blockIdx.x * 128 + wave * 32;
  const int lq = lane & 31, hi = lane >> 5;

  const char* kbase = (const char*)Kb + ((size_t)b * 2048 * 512 + g * 128) * 2;
  const char* vbase = (const char*)Vt + ((size_t)(b * 512 + g * 128) * 2048) * 2;
  int kRow[4], kOff[4], vRow[4], vOff[4];
#pragma unroll
  for (int i = 0; i < 4; ++i) {
    const int off = (i * 256 + tid) * 16;
    const int r = off >> 8, c = off & 255;
    kRow[i] = r; kOff[i] = c ^ ((r & 7) << 4);
    const int rv = off >> 7, cv = off & 127;
    vRow[i] = rv; vOff[i] = cv ^ ((rv & 7) << 4);
  }

#pragma unroll
  for (int i = 0; i < 4; ++i) {
    GLOAD_LDS16(kbase + (size_t)kRow[i] * 1024 + kOff[i],
                (char*)Ks[0] + (i * 256 + tid) * 16);
    GLOAD_LDS16(vbase + (size_t)vRow[i] * 4096 + vOff[i],
                (char*)Vs[0] + (i * 256 + tid) * 16);
  }

  short8 qf[8];
  {
    const ushort* qp = Q + (size_t)(b * 2048 + q0w + lq) * 2048 + h * 128 + hi * 8;
#pragma unroll
    for (int dblk = 0; dblk < 8; ++dblk)
      qf[dblk] = *reinterpret_cast<const short8*>(qp + dblk * 16);
  }

  float m_s = -3.0e38f, l_s = 0.f;
  f32x16 o[4] = {};
  const float sc2 = 0.08838834764831843f * 1.44269504088896340736f;

  __syncthreads();

  for (int t = 0; t < 32; ++t) {
    const int cur = t & 1;
    if (t < 31) {
      const int kv0 = (t + 1) * 64;
#pragma unroll
      for (int i = 0; i < 4; ++i) {
        GLOAD_LDS16(kbase + (size_t)(kv0 + kRow[i]) * 1024 + kOff[i],
                    (char*)Ks[cur ^ 1] + (i * 256 + tid) * 16);
        GLOAD_LDS16(vbase + (size_t)vRow[i] * 4096 + kv0 * 2 + vOff[i],
                    (char*)Vs[cur ^ 1] + (i * 256 + tid) * 16);
      }
    }

    // S^T = K Q^T
    const char* ksb = (const char*)Ks[cur];
    f32x16 st0 = {}, st1 = {};
    const int ksw = (lq & 7) << 4;
    __builtin_amdgcn_s_setprio(1);
#pragma unroll
    for (int dblk = 0; dblk < 8; ++dblk) {
      const int cb = (dblk * 32 + 16 * hi) ^ ksw;
      short8 kf0 = *reinterpret_cast<const short8*>(ksb + lq * 256 + cb);
      short8 kf1 = *reinterpret_cast<const short8*>(ksb + (32 + lq) * 256 + cb);
      st0 = __builtin_amdgcn_mfma_f32_32x32x16_bf16(kf0, qf[dblk], st0, 0, 0, 0);
      st1 = __builtin_amdgcn_mfma_f32_32x32x16_bf16(kf1, qf[dblk], st1, 0, 0, 0);
    }
    __builtin_amdgcn_s_setprio(0);

    // online softmax (tree reductions, depth 5)
    float mx[16];
#pragma unroll
    for (int r = 0; r < 16; ++r) mx[r] = fmaxf(st0[r], st1[r]);
#pragma unroll
    for (int s = 8; s >= 1; s >>= 1)
#pragma unroll
      for (int r = 0; r < s; ++r) mx[r] = fmaxf(mx[r], mx[r + s]);
    float pm = fmaxf(mx[0], __shfl_xor(mx[0], 32, 64));
    const float msc = pm * sc2;

    if (__any(msc > m_s + 8.f)) {  // defer-max
      const float mnew = fmaxf(m_s, msc);
      const float alpha = exp2f(m_s - mnew);
      m_s = mnew;
      l_s *= alpha;
#pragma unroll
      for (int r = 0; r < 16; ++r) {
        const int qr = (r & 3) + 8 * (r >> 2) + 4 * hi;
        const float ar = __shfl(alpha, qr, 64);
#pragma unroll
        for (int dblk = 0; dblk < 4; ++dblk) o[dblk][r] *= ar;
      }
    }

    float sm[16];
#pragma unroll
    for (int r = 0; r < 16; ++r) {
      st0[r] = exp2f(fmaf(st0[r], sc2, -m_s));
      st1[r] = exp2f(fmaf(st1[r], sc2, -m_s));
      sm[r] = st0[r] + st1[r];
    }
#pragma unroll
    for (int s = 8; s >= 1; s >>= 1)
#pragma unroll
      for (int r = 0; r < s; ++r) sm[r] += sm[r + s];
    float rs = sm[0];
    rs += __shfl_xor(rs, 32, 64);
    l_s += rs;

    // pack P -> bf16 A-frags
    short8 pa[4];
#pragma unroll
    for (int half = 0; half < 2; ++half) {
      const f32x16 pt = half ? st1 : st0;
#pragma unroll
      for (int kk = 0; kk < 2; ++kk) {
        const int Rx = kk * 8;
        uint w0, w1, w2, w3;
#pragma unroll
        for (int s2 = 0; s2 < 2; ++s2) {
          const int s = s2 * 2;
          const float x0 = pt[Rx + s],     x1 = pt[Rx + s + 1];
          const float y0 = pt[Rx + 4 + s], y1 = pt[Rx + 4 + s + 1];
          uint x, y;
          asm("v_cvt_pk_bf16_f32 %0, %1, %2" : "=v"(x) : "v"(x0), "v"(x1));
          asm("v_cvt_pk_bf16_f32 %0, %1, %2" : "=v"(y) : "v"(y0), "v"(y1));
          auto sw = __builtin_amdgcn_permlane32_swap(x, y, false, false);
          if (s2 == 0) { w0 = sw[0]; w2 = sw[1]; }
          else         { w1 = sw[0]; w3 = sw[1]; }
        }
        u32x4 wv = {w0, w1, w2, w3};
        pa[half * 2 + kk] = __builtin_bit_cast(short8, wv);
      }
    }

    // O += P V
    const char* vsb = (const char*)Vs[cur];
    __builtin_amdgcn_s_setprio(1);
#pragma unroll
    for (int dblk = 0; dblk < 4; ++dblk) {
      const int rv = dblk * 32 + lq;
      const int vsw = (rv & 7) << 4;
#pragma unroll
      for (int ks = 0; ks < 4; ++ks) {
        short8 vf = *reinterpret_cast<const short8*>(
            vsb + rv * 128 + ((ks * 32 + 16 * hi) ^ vsw));
        o[dblk] = __builtin_amdgcn_mfma_f32_32x32x16_bf16(pa[ks], vf, o[dblk], 0, 0, 0);
      }
    }
    __builtin_amdgcn_s_setprio(0);

    __syncthreads();
  }

  const float linv = 1.f / l_s;
#pragma unroll
  for (int r = 0; r < 16; ++r) {
    const int qr = (r & 3) + 8 * (r >> 2) + 4 * hi;
    const float lv = __shfl(linv, qr, 64);
    ushort* mp = Mid + (size_t)(b * 2048 + q0w + qr) * 2048 + h * 128 + lq;
#pragma unroll
    for (int dblk = 0; dblk < 4; ++dblk)
      mp[dblk * 32] = f2bf(o[dblk][r] * lv);
  }
}

// ------------------------------------------------------------------- launcher
extern "C" void kernel_launch(void* const* d_in, const int* in_sizes, int n_in,
                              void* d_out, int out_size, void* d_ws, size_t ws_size,
                              hipStream_t stream) {
  const float* X  = (const float*)d_in[0];
  const float* Wq = (const float*)d_in[1];
  const float* bq = (const float*)d_in[2];
  const float* Wk = (const float*)d_in[3];
  const float* bk = (const float*)d_in[4];
  const float* Wv = (const float*)d_in[5];
  const float* bv = (const float*)d_in[6];
  const float* Wo = (const float*)d_in[7];
  const float* bo = (const float*)d_in[8];
  float* Out = (float*)d_out;

  char* ws = (char*)d_ws;
  ushort* Xb   = (ushort*)(ws);              // 16 MB  [B*S,2048]
  ushort* Wqb  = (ushort*)(ws + 16777216);   //  8 MB
  ushort* Wkb  = (ushort*)(ws + 25165824);   //  2 MB
  ushort* Wvb  = (ushort*)(ws + 27262976);   //  2 MB
  ushort* Wob  = (ushort*)(ws + 29360128);   //  8 MB
  ushort* Qb   = (ushort*)(ws + 37748736);   // 16 MB  [B*S,2048]
  ushort* Kbuf = (ushort*)(ws + 54525952);   //  4 MB  [B*S,512]
  ushort* Vtb  = (ushort*)(ws + 58720256);   //  4 MB  [B,512,S] (transposed)
  ushort* Midb = (ushort*)(ws + 62914560);   // 16 MB  [B*S,2048]

  auto cast = [&](const float* src, ushort* dst, int n) {
    int n4 = n >> 2;
    int blocks = (n4 + 255) >> 8;
    if (blocks > 2048) blocks = 2048;
    cast_f32_to_bf16<<<dim3(blocks), dim3(256), 0, stream>>>(src, dst, n4);
  };
  cast(X,  Xb,  8388608);
  cast(Wq, Wqb, 4194304);
  cast(Wk, Wkb, 1048576);
  cast(Wv, Wvb, 1048576);
  cast(Wo, Wob, 4194304);

  qkv_gemm8<<<dim3(192), dim3(512), 0, stream>>>(Xb, Wqb, Wkb, Wvb, bq, bk, bv,
                                                 Qb, Kbuf, Vtb);
  attn_fwd<<<dim3(16, 16, 2), 256, 0, stream>>>(Qb, Kbuf, Vtb, Midb);
  out_gemm8<<<dim3(256), dim3(512), 0, stream>>>(Midb, Wob, bo, Out);
}